// Round 1
// baseline (155.682 us; speedup 1.0000x reference)
//
#include <hip/hip_runtime.h>
#include <math.h>

#define N_ATOMS 100000
#define N_EDGES 6400000

// ZBL repulsion: E = sum over edges of 0.5*Zi*Zj/dr * f(dist) * cos_cutoff(dr)
// ~98% of edges have dr >= R_MAX=6 -> exact zero contribution (cos(pi) rounds
// to -1 in fp32 in the reference). Branch on d2 < 36 to skip transcendentals
// and the Z gather for dead edges (exec-masked lanes issue no memory requests).
__global__ __launch_bounds__(256, 4)
void zbl_kernel(const float* __restrict__ R,
                const int*   __restrict__ Z,
                const int*   __restrict__ idx,
                const float* __restrict__ a_exp,
                const float* __restrict__ a_num,
                const float* __restrict__ coef,
                const float* __restrict__ expo,
                float*       __restrict__ out)
{
    __shared__ float powz[64];      // Z^a_exp LUT, Z in [1,50)
    __shared__ float wave_part[4];  // 256 threads = 4 waves

    const float aexp     = a_exp[0];
    const float inv_anum = 1.0f / a_num[0];
    const float c0 = coef[0], c1 = coef[1], c2 = coef[2], c3 = coef[3];
    const float e0 = expo[0], e1 = expo[1], e2 = expo[2], e3 = expo[3];

    const int t = threadIdx.x;
    if (t < 64) powz[t] = __powf((float)t, aexp);  // powf(0,.23)=0, fine
    __syncthreads();

    const int4* idx_i4 = (const int4*)idx;              // idx[0,:]
    const int4* idx_j4 = (const int4*)(idx + N_EDGES);  // idx[1,:]
    const int n4 = N_EDGES / 4;
    const int tid    = blockIdx.x * blockDim.x + t;
    const int stride = gridDim.x * blockDim.x;

    const float PI_OVER_RMAX = 0.52359877559829887f;  // pi/6

    float acc = 0.0f;
    for (int k = tid; k < n4; k += stride) {
        int4 ii = idx_i4[k];
        int4 jj = idx_j4[k];
#pragma unroll
        for (int u = 0; u < 4; ++u) {
            int i = (&ii.x)[u];
            int j = (&jj.x)[u];
            if ((unsigned)i < N_ATOMS && (unsigned)j < N_ATOMS) {
                float xi = R[3 * i + 0], yi = R[3 * i + 1], zi = R[3 * i + 2];
                float xj = R[3 * j + 0], yj = R[3 * j + 1], zj = R[3 * j + 2];
                float dx = xj - xi, dy = yj - yi, dz = zj - zi;
                float d2 = dx * dx + dy * dy + dz * dz;
                if (d2 < 36.0f) {
                    float dr = fmaxf(sqrtf(d2), 0.02f);  // clip [0.02, 6)
                    int Zi = Z[i], Zj = Z[j];
                    float dist = dr * (powz[Zi & 63] + powz[Zj & 63]) * inv_anum;
                    float f = c0 * __expf(-e0 * dist) + c1 * __expf(-e1 * dist)
                            + c2 * __expf(-e2 * dist) + c3 * __expf(-e3 * dist);
                    float cc = 0.5f * (__cosf(PI_OVER_RMAX * dr) + 1.0f);
                    acc += 0.5f * (float)(Zi * Zj) / dr * f * cc;
                }
            }
        }
    }

    // wave (64-lane) shuffle reduction
#pragma unroll
    for (int off = 32; off > 0; off >>= 1)
        acc += __shfl_down(acc, off, 64);

    const int lane = t & 63;
    const int wave = t >> 6;
    if (lane == 0) wave_part[wave] = acc;
    __syncthreads();
    if (t == 0) {
        float s = wave_part[0] + wave_part[1] + wave_part[2] + wave_part[3];
        atomicAdd(out, s);
    }
}

extern "C" void kernel_launch(void* const* d_in, const int* in_sizes, int n_in,
                              void* d_out, int out_size, void* d_ws, size_t ws_size,
                              hipStream_t stream) {
    const float* R     = (const float*)d_in[0];
    const int*   Z     = (const int*)d_in[1];
    const int*   idx   = (const int*)d_in[2];
    const float* a_exp = (const float*)d_in[3];
    const float* a_num = (const float*)d_in[4];
    const float* coef  = (const float*)d_in[5];
    const float* expo  = (const float*)d_in[6];
    float* out = (float*)d_out;

    // d_out is poisoned 0xAA before every timed launch -> zero it (capture-safe)
    hipMemsetAsync(out, 0, sizeof(float), stream);

    // 1024 blocks = 4 blocks/CU at 256 threads; grid-stride ~6 int4 iters/thread
    zbl_kernel<<<1024, 256, 0, stream>>>(R, Z, idx, a_exp, a_num, coef, expo, out);
}

// Round 2
// 152.416 us; speedup vs baseline: 1.0214x; 1.0214x over previous
//
#include <hip/hip_runtime.h>
#include <math.h>

#define N_ATOMS 100000
#define N_EDGES 6400000

// Prep: pack (x,y,z,Z) into one aligned float4 per atom so the per-edge gather
// is a single global_load_dwordx4 (1 cacheline) instead of 3-4 scattered dwords.
__global__ __launch_bounds__(256)
void pack_atoms(const float* __restrict__ R, const int* __restrict__ Z,
                float4* __restrict__ P) {
    int i = blockIdx.x * blockDim.x + threadIdx.x;
    if (i < N_ATOMS) {
        P[i] = make_float4(R[3 * i + 0], R[3 * i + 1], R[3 * i + 2], (float)Z[i]);
    }
}

// ZBL repulsion: E = sum over edges of 0.5*Zi*Zj/dr * f(dist) * cos_cutoff(dr)
// ~98% of edges have dr >= R_MAX=6 -> exact zero (cos(pi)=-1 in fp32 in the
// reference). Branch on d2 < 36 to skip all transcendentals for dead edges.
// Gather-request-throughput bound: one dwordx4 per atom is the whole gather.
__global__ __launch_bounds__(256, 8)
void zbl_packed(const float4* __restrict__ P,
                const int*    __restrict__ idx,
                const float*  __restrict__ a_exp,
                const float*  __restrict__ a_num,
                const float*  __restrict__ coef,
                const float*  __restrict__ expo,
                float*        __restrict__ out)
{
    __shared__ float powz[64];      // Z^a_exp LUT, Z in [1,50)
    __shared__ float wave_part[4];  // 256 threads = 4 waves

    const float aexp     = a_exp[0];
    const float inv_anum = 1.0f / a_num[0];
    const float c0 = coef[0], c1 = coef[1], c2 = coef[2], c3 = coef[3];
    const float e0 = expo[0], e1 = expo[1], e2 = expo[2], e3 = expo[3];

    const int t = threadIdx.x;
    if (t < 64) powz[t] = __powf((float)t, aexp);
    __syncthreads();

    const int4* idx_i4 = (const int4*)idx;              // idx[0,:]
    const int4* idx_j4 = (const int4*)(idx + N_EDGES);  // idx[1,:]
    const int n4 = N_EDGES / 4;                          // 1.6M, exact
    const int tid    = blockIdx.x * blockDim.x + t;
    const int stride = gridDim.x * blockDim.x;

    const float PI_OVER_RMAX = 0.52359877559829887f;  // pi/6

    float acc = 0.0f;
    for (int k = tid; k < n4; k += stride) {
        int4 ii = idx_i4[k];
        int4 jj = idx_j4[k];
#pragma unroll
        for (int u = 0; u < 4; ++u) {
            int i = (&ii.x)[u];
            int j = (&jj.x)[u];
            if ((unsigned)i < N_ATOMS && (unsigned)j < N_ATOMS) {
                float4 pi = P[i];
                float4 pj = P[j];
                float dx = pj.x - pi.x, dy = pj.y - pi.y, dz = pj.z - pi.z;
                float d2 = dx * dx + dy * dy + dz * dz;
                if (d2 < 36.0f) {
                    float dr = fmaxf(sqrtf(d2), 0.02f);  // clip [0.02, 6)
                    int zi = (int)pi.w, zj = (int)pj.w;
                    float dist = dr * (powz[zi & 63] + powz[zj & 63]) * inv_anum;
                    float f = c0 * __expf(-e0 * dist) + c1 * __expf(-e1 * dist)
                            + c2 * __expf(-e2 * dist) + c3 * __expf(-e3 * dist);
                    float cc = 0.5f * (__cosf(PI_OVER_RMAX * dr) + 1.0f);
                    acc += 0.5f * pi.w * pj.w / dr * f * cc;  // Zi*Zj exact in fp32
                }
            }
        }
    }

    // wave (64-lane) shuffle reduction
#pragma unroll
    for (int off = 32; off > 0; off >>= 1)
        acc += __shfl_down(acc, off, 64);

    const int lane = t & 63;
    const int wave = t >> 6;
    if (lane == 0) wave_part[wave] = acc;
    __syncthreads();
    if (t == 0) {
        float s = wave_part[0] + wave_part[1] + wave_part[2] + wave_part[3];
        atomicAdd(out, s);
    }
}

// Fallback (ws too small): previous unpacked version.
__global__ __launch_bounds__(256, 8)
void zbl_unpacked(const float* __restrict__ R, const int* __restrict__ Z,
                  const int* __restrict__ idx,
                  const float* __restrict__ a_exp, const float* __restrict__ a_num,
                  const float* __restrict__ coef, const float* __restrict__ expo,
                  float* __restrict__ out)
{
    __shared__ float powz[64];
    __shared__ float wave_part[4];
    const float aexp = a_exp[0];
    const float inv_anum = 1.0f / a_num[0];
    const float c0 = coef[0], c1 = coef[1], c2 = coef[2], c3 = coef[3];
    const float e0 = expo[0], e1 = expo[1], e2 = expo[2], e3 = expo[3];
    const int t = threadIdx.x;
    if (t < 64) powz[t] = __powf((float)t, aexp);
    __syncthreads();
    const int4* idx_i4 = (const int4*)idx;
    const int4* idx_j4 = (const int4*)(idx + N_EDGES);
    const int n4 = N_EDGES / 4;
    const int tid = blockIdx.x * blockDim.x + t;
    const int stride = gridDim.x * blockDim.x;
    const float PI_OVER_RMAX = 0.52359877559829887f;
    float acc = 0.0f;
    for (int k = tid; k < n4; k += stride) {
        int4 ii = idx_i4[k];
        int4 jj = idx_j4[k];
#pragma unroll
        for (int u = 0; u < 4; ++u) {
            int i = (&ii.x)[u];
            int j = (&jj.x)[u];
            if ((unsigned)i < N_ATOMS && (unsigned)j < N_ATOMS) {
                float xi = R[3*i], yi = R[3*i+1], zi_ = R[3*i+2];
                float xj = R[3*j], yj = R[3*j+1], zj_ = R[3*j+2];
                float dx = xj - xi, dy = yj - yi, dz = zj_ - zi_;
                float d2 = dx*dx + dy*dy + dz*dz;
                if (d2 < 36.0f) {
                    float dr = fmaxf(sqrtf(d2), 0.02f);
                    int Zi = Z[i], Zj = Z[j];
                    float dist = dr * (powz[Zi & 63] + powz[Zj & 63]) * inv_anum;
                    float f = c0*__expf(-e0*dist) + c1*__expf(-e1*dist)
                            + c2*__expf(-e2*dist) + c3*__expf(-e3*dist);
                    float cc = 0.5f * (__cosf(PI_OVER_RMAX * dr) + 1.0f);
                    acc += 0.5f * (float)(Zi*Zj) / dr * f * cc;
                }
            }
        }
    }
#pragma unroll
    for (int off = 32; off > 0; off >>= 1)
        acc += __shfl_down(acc, off, 64);
    const int lane = t & 63;
    const int wave = t >> 6;
    if (lane == 0) wave_part[wave] = acc;
    __syncthreads();
    if (t == 0)
        atomicAdd(out, wave_part[0] + wave_part[1] + wave_part[2] + wave_part[3]);
}

extern "C" void kernel_launch(void* const* d_in, const int* in_sizes, int n_in,
                              void* d_out, int out_size, void* d_ws, size_t ws_size,
                              hipStream_t stream) {
    const float* R     = (const float*)d_in[0];
    const int*   Z     = (const int*)d_in[1];
    const int*   idx   = (const int*)d_in[2];
    const float* a_exp = (const float*)d_in[3];
    const float* a_num = (const float*)d_in[4];
    const float* coef  = (const float*)d_in[5];
    const float* expo  = (const float*)d_in[6];
    float* out = (float*)d_out;

    hipMemsetAsync(out, 0, sizeof(float), stream);  // d_out poisoned each call

    const size_t packed_bytes = (size_t)N_ATOMS * sizeof(float4);
    if (ws_size >= packed_bytes) {
        float4* P = (float4*)d_ws;
        pack_atoms<<<(N_ATOMS + 255) / 256, 256, 0, stream>>>(R, Z, P);
        // 2048 blocks * 4 waves = 8192 waves = 32 waves/CU (full occupancy)
        zbl_packed<<<2048, 256, 0, stream>>>(P, idx, a_exp, a_num, coef, expo, out);
    } else {
        zbl_unpacked<<<2048, 256, 0, stream>>>(R, Z, idx, a_exp, a_num, coef, expo, out);
    }
}

// Round 3
// 148.272 us; speedup vs baseline: 1.0500x; 1.0280x over previous
//
#include <hip/hip_runtime.h>
#include <math.h>

#define N_ATOMS 100000
#define N_EDGES 6400000

// Prep: pack (x,y,z,Z) into one aligned float4 per atom -> per-edge gather is
// a single global_load_dwordx4 touching exactly one cacheline.
__global__ __launch_bounds__(256)
void pack_atoms(const float* __restrict__ R, const int* __restrict__ Z,
                float4* __restrict__ P) {
    int i = blockIdx.x * blockDim.x + threadIdx.x;
    if (i < N_ATOMS) {
        P[i] = make_float4(R[3 * i + 0], R[3 * i + 1], R[3 * i + 2], (float)Z[i]);
    }
}

// Latency/MLP-bound random-gather kernel. Key change vs R2: the 8 gathers per
// int4 iteration are UNCONDITIONAL (index clamped branchlessly; validity folded
// into the contribution predicate), so they sit in one basic block and the
// compiler keeps all 8 in flight per wave instead of 2 (exec-mask branches in
// R2 serialized them -> only ~40 outstanding misses/CU -> 67us latency-bound).
__global__ __launch_bounds__(256)
void zbl_mlp(const float4* __restrict__ P,
             const int*    __restrict__ idx,
             const float*  __restrict__ a_exp,
             const float*  __restrict__ a_num,
             const float*  __restrict__ coef,
             const float*  __restrict__ expo,
             float*        __restrict__ out)
{
    __shared__ float powz[64];      // Z^a_exp LUT, Z in [1,50)
    __shared__ float wave_part[4];  // 256 threads = 4 waves

    const float aexp     = a_exp[0];
    const float inv_anum = 1.0f / a_num[0];
    const float c0 = coef[0], c1 = coef[1], c2 = coef[2], c3 = coef[3];
    const float e0 = expo[0], e1 = expo[1], e2 = expo[2], e3 = expo[3];

    const int t = threadIdx.x;
    if (t < 64) powz[t] = __powf((float)t, aexp);
    __syncthreads();

    const int4* idx_i4 = (const int4*)idx;              // idx[0,:]
    const int4* idx_j4 = (const int4*)(idx + N_EDGES);  // idx[1,:]
    const int n4 = N_EDGES / 4;                          // 1.6M, exact
    const int tid    = blockIdx.x * blockDim.x + t;
    const int stride = gridDim.x * blockDim.x;

    const float PI_OVER_RMAX = 0.52359877559829887f;  // pi/6

    float acc = 0.0f;
    for (int k = tid; k < n4; k += stride) {
        int4 ii = idx_i4[k];
        int4 jj = idx_j4[k];

        // ---- issue all 8 gathers, no branches in between ----
        float4 pa[4], pb[4];
        bool valid[4];
#pragma unroll
        for (int u = 0; u < 4; ++u) {
            int i = (&ii.x)[u];
            int j = (&jj.x)[u];
            valid[u] = ((unsigned)i < N_ATOMS) & ((unsigned)j < N_ATOMS);
            unsigned iu = min((unsigned)i, N_ATOMS - 1u);  // clamped load is safe
            unsigned ju = min((unsigned)j, N_ATOMS - 1u);
            pa[u] = P[iu];
            pb[u] = P[ju];
        }

        // ---- consume; expensive tail only for live (~2%) edges ----
#pragma unroll
        for (int u = 0; u < 4; ++u) {
            float dx = pb[u].x - pa[u].x;
            float dy = pb[u].y - pa[u].y;
            float dz = pb[u].z - pa[u].z;
            float d2 = dx * dx + dy * dy + dz * dz;
            if (valid[u] && d2 < 36.0f) {
                float dr = fmaxf(sqrtf(d2), 0.02f);  // clip [0.02, 6)
                int zi = (int)pa[u].w, zj = (int)pb[u].w;
                float dist = dr * (powz[zi & 63] + powz[zj & 63]) * inv_anum;
                float f = c0 * __expf(-e0 * dist) + c1 * __expf(-e1 * dist)
                        + c2 * __expf(-e2 * dist) + c3 * __expf(-e3 * dist);
                float cc = 0.5f * (__cosf(PI_OVER_RMAX * dr) + 1.0f);
                acc += 0.5f * pa[u].w * pb[u].w / dr * f * cc;
            }
        }
    }

    // wave (64-lane) shuffle reduction
#pragma unroll
    for (int off = 32; off > 0; off >>= 1)
        acc += __shfl_down(acc, off, 64);

    const int lane = t & 63;
    const int wave = t >> 6;
    if (lane == 0) wave_part[wave] = acc;
    __syncthreads();
    if (t == 0) {
        float s = wave_part[0] + wave_part[1] + wave_part[2] + wave_part[3];
        atomicAdd(out, s);
    }
}

// Fallback if ws can't hold the packed table (unpacked, same MLP structure).
__global__ __launch_bounds__(256)
void zbl_fallback(const float* __restrict__ R, const int* __restrict__ Z,
                  const int* __restrict__ idx,
                  const float* __restrict__ a_exp, const float* __restrict__ a_num,
                  const float* __restrict__ coef, const float* __restrict__ expo,
                  float* __restrict__ out)
{
    __shared__ float powz[64];
    __shared__ float wave_part[4];
    const float aexp = a_exp[0];
    const float inv_anum = 1.0f / a_num[0];
    const float c0 = coef[0], c1 = coef[1], c2 = coef[2], c3 = coef[3];
    const float e0 = expo[0], e1 = expo[1], e2 = expo[2], e3 = expo[3];
    const int t = threadIdx.x;
    if (t < 64) powz[t] = __powf((float)t, aexp);
    __syncthreads();
    const int4* idx_i4 = (const int4*)idx;
    const int4* idx_j4 = (const int4*)(idx + N_EDGES);
    const int n4 = N_EDGES / 4;
    const int tid = blockIdx.x * blockDim.x + t;
    const int stride = gridDim.x * blockDim.x;
    const float PI_OVER_RMAX = 0.52359877559829887f;
    float acc = 0.0f;
    for (int k = tid; k < n4; k += stride) {
        int4 ii = idx_i4[k];
        int4 jj = idx_j4[k];
#pragma unroll
        for (int u = 0; u < 4; ++u) {
            int i = (&ii.x)[u];
            int j = (&jj.x)[u];
            if ((unsigned)i < N_ATOMS && (unsigned)j < N_ATOMS) {
                float dx = R[3*j] - R[3*i];
                float dy = R[3*j+1] - R[3*i+1];
                float dz = R[3*j+2] - R[3*i+2];
                float d2 = dx*dx + dy*dy + dz*dz;
                if (d2 < 36.0f) {
                    float dr = fmaxf(sqrtf(d2), 0.02f);
                    int Zi = Z[i], Zj = Z[j];
                    float dist = dr * (powz[Zi & 63] + powz[Zj & 63]) * inv_anum;
                    float f = c0*__expf(-e0*dist) + c1*__expf(-e1*dist)
                            + c2*__expf(-e2*dist) + c3*__expf(-e3*dist);
                    float cc = 0.5f * (__cosf(PI_OVER_RMAX * dr) + 1.0f);
                    acc += 0.5f * (float)(Zi*Zj) / dr * f * cc;
                }
            }
        }
    }
#pragma unroll
    for (int off = 32; off > 0; off >>= 1)
        acc += __shfl_down(acc, off, 64);
    const int lane = t & 63;
    const int wave = t >> 6;
    if (lane == 0) wave_part[wave] = acc;
    __syncthreads();
    if (t == 0)
        atomicAdd(out, wave_part[0] + wave_part[1] + wave_part[2] + wave_part[3]);
}

extern "C" void kernel_launch(void* const* d_in, const int* in_sizes, int n_in,
                              void* d_out, int out_size, void* d_ws, size_t ws_size,
                              hipStream_t stream) {
    const float* R     = (const float*)d_in[0];
    const int*   Z     = (const int*)d_in[1];
    const int*   idx   = (const int*)d_in[2];
    const float* a_exp = (const float*)d_in[3];
    const float* a_num = (const float*)d_in[4];
    const float* coef  = (const float*)d_in[5];
    const float* expo  = (const float*)d_in[6];
    float* out = (float*)d_out;

    hipMemsetAsync(out, 0, sizeof(float), stream);  // d_out poisoned each call

    const size_t packed_bytes = (size_t)N_ATOMS * sizeof(float4);
    if (ws_size >= packed_bytes) {
        float4* P = (float4*)d_ws;
        pack_atoms<<<(N_ATOMS + 255) / 256, 256, 0, stream>>>(R, Z, P);
        zbl_mlp<<<2048, 256, 0, stream>>>(P, idx, a_exp, a_num, coef, expo, out);
    } else {
        zbl_fallback<<<2048, 256, 0, stream>>>(R, Z, idx, a_exp, a_num, coef, expo, out);
    }
}

// Round 4
// 121.972 us; speedup vs baseline: 1.2764x; 1.2156x over previous
//
#include <hip/hip_runtime.h>
#include <math.h>

#define N_ATOMS 100000
#define N_EDGES 6400000
#define NZB 50000          // ceil(N_ATOMS/2) z-nibble bytes
#define TBL_BYTES (N_ATOMS * 16)           // float4 P table
#define XY_OFF    TBL_BYTES                // 1,600,000 (16B aligned)
#define Z_OFF     (XY_OFF + N_ATOMS)       // 1,700,000 (16B aligned)
#define WS_NEED   (Z_OFF + NZB)

// cell(x): width-6 cells over [-48,48], clamped. Cell gap >= 2 in any dim
// guarantees |delta| >= 6 (minus ~1e-5 quantization slack) -> dr >= 6 ->
// cos_cutoff == 0 exactly in fp32 -> zero contribution. Conservative reject.
__device__ __forceinline__ int cell6(float x) {
    return min(max((int)((x + 48.0f) * (1.0f / 6.0f)), 0), 15);
}

__global__ __launch_bounds__(256)
void build_tables(const float* __restrict__ R, const int* __restrict__ Z,
                  float4* __restrict__ P, unsigned char* __restrict__ gxy,
                  unsigned char* __restrict__ gz) {
    int i = blockIdx.x * blockDim.x + threadIdx.x;
    if (i < N_ATOMS) {
        float x = R[3 * i], y = R[3 * i + 1], z = R[3 * i + 2];
        P[i] = make_float4(x, y, z, (float)Z[i]);
        gxy[i] = (unsigned char)(cell6(x) | (cell6(y) << 4));
    }
    if (i < NZB) {  // one thread per packed z-byte (2 atoms) -> no write race
        int a0 = 2 * i, a1 = 2 * i + 1;
        int c0 = cell6(R[3 * a0 + 2]);
        int c1 = (a1 < N_ATOMS) ? cell6(R[3 * a1 + 2]) : 0;
        gz[i] = (unsigned char)(c0 | (c1 << 4));
    }
}

// L1-miss-path bound fix: 150 KB LDS prefilter (cell codes for all atoms).
// Only ~10.5% of edges pass the conservative cell test -> exec-masked float4
// gathers cut the L2->L1 line-fill count ~9.5x (that path measured ~3.1
// cyc/fill and was the R2/R3 wall at 65us).
__global__ __launch_bounds__(1024)
void zbl_prefilter(const float4* __restrict__ P,
                   const unsigned char* __restrict__ gxy,
                   const unsigned char* __restrict__ gz,
                   const int*    __restrict__ idx,
                   const float*  __restrict__ a_exp,
                   const float*  __restrict__ a_num,
                   const float*  __restrict__ coef,
                   const float*  __restrict__ expo,
                   float*        __restrict__ out)
{
    __shared__ __align__(16) unsigned char sxy[N_ATOMS];  // 100 KB
    __shared__ __align__(16) unsigned char sz[NZB];       // 50 KB
    __shared__ float powz[64];
    __shared__ float wave_part[16];

    const int t = threadIdx.x;

    // cooperative LDS table load (uint4-vectorized; sizes divide 16 exactly)
    {
        const uint4* s = (const uint4*)gxy;
        uint4*       d = (uint4*)sxy;
        for (int k = t; k < N_ATOMS / 16; k += 1024) d[k] = s[k];
        const uint4* s2 = (const uint4*)gz;
        uint4*       d2 = (uint4*)sz;
        for (int k = t; k < NZB / 16; k += 1024) d2[k] = s2[k];
    }

    const float aexp     = a_exp[0];
    const float inv_anum = 1.0f / a_num[0];
    const float c0 = coef[0], c1 = coef[1], c2 = coef[2], c3 = coef[3];
    const float e0 = expo[0], e1 = expo[1], e2 = expo[2], e3 = expo[3];
    if (t < 64) powz[t] = __powf((float)t, aexp);
    __syncthreads();

    const int4* idx_i4 = (const int4*)idx;              // idx[0,:]
    const int4* idx_j4 = (const int4*)(idx + N_EDGES);  // idx[1,:]
    const int n4 = N_EDGES / 4;                          // 1.6M exact
    const int tid    = blockIdx.x * blockDim.x + t;
    const int stride = gridDim.x * blockDim.x;

    const float PI_OVER_RMAX = 0.52359877559829887f;  // pi/6

    float acc = 0.0f;
    for (int k = tid; k < n4; k += stride) {
        int4 ii = idx_i4[k];
        int4 jj = idx_j4[k];

        unsigned ia[4], jb[4];
        bool pass[4];
        // stage 1: xy cell test for all 4 edges (8 LDS byte reads, batched)
#pragma unroll
        for (int u = 0; u < 4; ++u) {
            int i = (&ii.x)[u];
            int j = (&jj.x)[u];
            bool valid = ((unsigned)i < N_ATOMS) & ((unsigned)j < N_ATOMS);
            unsigned a = min((unsigned)i, N_ATOMS - 1u);
            unsigned b = min((unsigned)j, N_ATOMS - 1u);
            ia[u] = a; jb[u] = b;
            int ci = sxy[a], cj = sxy[b];
            int dxy = abs((ci & 15) - (cj & 15)) | abs((ci >> 4) - (cj >> 4));
            pass[u] = valid & (dxy <= 1);
        }
        // stage 2: z test + sparse gather + physics (exec-masked, ~10% lanes)
#pragma unroll
        for (int u = 0; u < 4; ++u) {
            if (pass[u]) {
                unsigned a = ia[u], b = jb[u];
                int zi = (sz[a >> 1] >> ((a & 1) << 2)) & 15;
                int zj = (sz[b >> 1] >> ((b & 1) << 2)) & 15;
                if (abs(zi - zj) <= 1) {
                    float4 pa = P[a];
                    float4 pb = P[b];
                    float dx = pb.x - pa.x, dy = pb.y - pa.y, dz = pb.z - pa.z;
                    float d2 = dx * dx + dy * dy + dz * dz;
                    if (d2 < 36.0f) {
                        float dr = fmaxf(sqrtf(d2), 0.02f);  // clip [0.02, 6)
                        int za = (int)pa.w, zb = (int)pb.w;
                        float dist = dr * (powz[za & 63] + powz[zb & 63]) * inv_anum;
                        float f = c0 * __expf(-e0 * dist) + c1 * __expf(-e1 * dist)
                                + c2 * __expf(-e2 * dist) + c3 * __expf(-e3 * dist);
                        float cc = 0.5f * (__cosf(PI_OVER_RMAX * dr) + 1.0f);
                        acc += 0.5f * pa.w * pb.w / dr * f * cc;
                    }
                }
            }
        }
    }

    // wave (64-lane) shuffle reduction, then 16-wave LDS reduction
#pragma unroll
    for (int off = 32; off > 0; off >>= 1)
        acc += __shfl_down(acc, off, 64);
    const int lane = t & 63;
    const int wave = t >> 6;
    if (lane == 0) wave_part[wave] = acc;
    __syncthreads();
    if (t == 0) {
        float s = 0.0f;
#pragma unroll
        for (int w = 0; w < 16; ++w) s += wave_part[w];
        atomicAdd(out, s);
    }
}

// Fallback (ws too small): R3 kernel, packed-gather MLP version.
__global__ __launch_bounds__(256)
void zbl_mlp(const float4* __restrict__ P, const int* __restrict__ idx,
             const float* __restrict__ a_exp, const float* __restrict__ a_num,
             const float* __restrict__ coef, const float* __restrict__ expo,
             float* __restrict__ out)
{
    __shared__ float powz[64];
    __shared__ float wave_part[4];
    const float aexp = a_exp[0];
    const float inv_anum = 1.0f / a_num[0];
    const float c0 = coef[0], c1 = coef[1], c2 = coef[2], c3 = coef[3];
    const float e0 = expo[0], e1 = expo[1], e2 = expo[2], e3 = expo[3];
    const int t = threadIdx.x;
    if (t < 64) powz[t] = __powf((float)t, aexp);
    __syncthreads();
    const int4* idx_i4 = (const int4*)idx;
    const int4* idx_j4 = (const int4*)(idx + N_EDGES);
    const int n4 = N_EDGES / 4;
    const int tid = blockIdx.x * blockDim.x + t;
    const int stride = gridDim.x * blockDim.x;
    const float PI_OVER_RMAX = 0.52359877559829887f;
    float acc = 0.0f;
    for (int k = tid; k < n4; k += stride) {
        int4 ii = idx_i4[k];
        int4 jj = idx_j4[k];
        float4 pa[4], pb[4];
        bool valid[4];
#pragma unroll
        for (int u = 0; u < 4; ++u) {
            int i = (&ii.x)[u], j = (&jj.x)[u];
            valid[u] = ((unsigned)i < N_ATOMS) & ((unsigned)j < N_ATOMS);
            pa[u] = P[min((unsigned)i, N_ATOMS - 1u)];
            pb[u] = P[min((unsigned)j, N_ATOMS - 1u)];
        }
#pragma unroll
        for (int u = 0; u < 4; ++u) {
            float dx = pb[u].x - pa[u].x, dy = pb[u].y - pa[u].y, dz = pb[u].z - pa[u].z;
            float d2 = dx * dx + dy * dy + dz * dz;
            if (valid[u] && d2 < 36.0f) {
                float dr = fmaxf(sqrtf(d2), 0.02f);
                int zi = (int)pa[u].w, zj = (int)pb[u].w;
                float dist = dr * (powz[zi & 63] + powz[zj & 63]) * inv_anum;
                float f = c0 * __expf(-e0 * dist) + c1 * __expf(-e1 * dist)
                        + c2 * __expf(-e2 * dist) + c3 * __expf(-e3 * dist);
                float cc = 0.5f * (__cosf(PI_OVER_RMAX * dr) + 1.0f);
                acc += 0.5f * pa[u].w * pb[u].w / dr * f * cc;
            }
        }
    }
#pragma unroll
    for (int off = 32; off > 0; off >>= 1)
        acc += __shfl_down(acc, off, 64);
    const int lane = t & 63, wave = t >> 6;
    if (lane == 0) wave_part[wave] = acc;
    __syncthreads();
    if (t == 0)
        atomicAdd(out, wave_part[0] + wave_part[1] + wave_part[2] + wave_part[3]);
}

extern "C" void kernel_launch(void* const* d_in, const int* in_sizes, int n_in,
                              void* d_out, int out_size, void* d_ws, size_t ws_size,
                              hipStream_t stream) {
    const float* R     = (const float*)d_in[0];
    const int*   Z     = (const int*)d_in[1];
    const int*   idx   = (const int*)d_in[2];
    const float* a_exp = (const float*)d_in[3];
    const float* a_num = (const float*)d_in[4];
    const float* coef  = (const float*)d_in[5];
    const float* expo  = (const float*)d_in[6];
    float* out = (float*)d_out;

    hipMemsetAsync(out, 0, sizeof(float), stream);  // d_out poisoned each call

    if (ws_size >= (size_t)WS_NEED) {
        float4*        P   = (float4*)d_ws;
        unsigned char* gxy = (unsigned char*)d_ws + XY_OFF;
        unsigned char* gz  = (unsigned char*)d_ws + Z_OFF;
        build_tables<<<(N_ATOMS + 255) / 256, 256, 0, stream>>>(R, Z, P, gxy, gz);
        // 150 KB LDS -> 1 block/CU; 256 blocks x 1024 threads = persistent grid
        zbl_prefilter<<<256, 1024, 0, stream>>>(P, gxy, gz, idx,
                                                a_exp, a_num, coef, expo, out);
    } else if (ws_size >= (size_t)TBL_BYTES) {
        float4* P = (float4*)d_ws;
        build_tables<<<(N_ATOMS + 255) / 256, 256, 0, stream>>>(
            R, Z, P, (unsigned char*)d_ws, (unsigned char*)d_ws);  // unused tails
        zbl_mlp<<<2048, 256, 0, stream>>>(P, idx, a_exp, a_num, coef, expo, out);
    }
}